// Round 15
// baseline (749.304 us; speedup 1.0000x reference)
//
#include <hip/hip_runtime.h>
#include <hip/hip_cooperative_groups.h>

namespace cg = cooperative_groups;

// RbfNet on MI355X — round 15: ONE cooperative mega-kernel (9 dispatches -> 1).
// r13/r14 showed each kernel is latency-class with ~10-15us per-dispatch overhead /
// gaps dominating (~100us of the 270 unaccounted by per-kernel estimates).
// Phases (grid.sync between): [zero cnt + wt prep] -> [fill] -> [layer0] ->
// [gemm_ul1] -> [conv1] -> [gemm_ul2] -> [conv2 + fused T] -> [layer3].
// Math structure unchanged from r11-r14:
//   UL[j] = [x_j @ cW (p-major, 512) | x_j @ fW (64)]  (dense MFMA GEMM)
//   conv(x)[i] = sum_e w0*U[j,p] + w1*U[j,p+1]         (1 uint load/edge, pair-packed)
//   layer3 via T[j][p] = ansc2[j] @ cW3[p] (R^2)       (lane-parallel edge gather)
// Edge record (4B): j(15b) | p(3b) | round(w0*16383)(14b); w1 = 1-w0. Self-edges dropped.

#define CAP 48

typedef __attribute__((ext_vector_type(8))) short short8;
typedef __attribute__((ext_vector_type(4))) short short4v;
typedef __attribute__((ext_vector_type(4))) float f32x4;

__device__ __forceinline__ short bf16s(float f) {   // fp32 -> bf16 RNE
  unsigned u = __float_as_uint(f);
  return (short)((u + 0x7FFF + ((u >> 16) & 1)) >> 16);
}
__device__ __forceinline__ float b2f(unsigned short s) {
  return __uint_as_float(((unsigned)s) << 16);
}

struct MegaParams {
  const float* X; const int* fi; const int* fj; const float* dist;
  const float* cW0; const float* cb0; const float* fW0; const float* fb0;
  const float* cW1; const float* cb1; const float* fW1; const float* fb1;
  const float* cW2; const float* cb2; const float* fW2; const float* fb2;
  const float* cW3; const float* cb3; const float* fW3; const float* fb3;
  unsigned short* UL; unsigned short* ansc0; unsigned short* ansc1;
  float* ans1; float* T; short* wt1; short* wt2; int* jw; int* cnt;
  float* out; int n; int nE;
};

// ---- dense MFMA GEMM phase: UL[n,576] = Xb[n,64] @ WTul^T (block-stride over 16-node tiles)
__device__ __forceinline__ void gemm_ul_phase(
    const unsigned short* __restrict__ Xb, const short* __restrict__ WTul,
    unsigned short* __restrict__ UL, int n, char* smemRaw) {
  short* sUL = (short*)smemRaw;             // 16 x 584 shorts = 18688 B
  const int lane = threadIdx.x & 63;
  const int w = threadIdx.x >> 6;
  const int mrow = lane & 15;
  const int quad = lane >> 4;
  for (int tile = blockIdx.x; tile * 16 < n; tile += gridDim.x) {
    __syncthreads();                        // LDS reuse guard across iterations
    const int nodeBase = tile * 16;
    const int bnode = min(nodeBase + mrow, n - 1);
    const unsigned short* bBase = Xb + (size_t)bnode * 64 + quad * 8;
    short8 b0 = *(const short8*)(bBase);
    short8 b1 = *(const short8*)(bBase + 32);
    #pragma unroll
    for (int t = 0; t < 9; ++t) {
      const int ct = w * 9 + t;
      const short* aBase = WTul + (size_t)(ct * 16 + mrow) * 64 + quad * 8;
      short8 a0 = *(const short8*)(aBase);
      short8 a1 = *(const short8*)(aBase + 32);
      f32x4 acc = {0, 0, 0, 0};
      acc = __builtin_amdgcn_mfma_f32_16x16x32_bf16(a0, b0, acc, 0, 0, 0);
      acc = __builtin_amdgcn_mfma_f32_16x16x32_bf16(a1, b1, acc, 0, 0, 0);
      short4v pk;
      #pragma unroll
      for (int reg = 0; reg < 4; ++reg) pk[reg] = bf16s(acc[reg]);
      *(short4v*)(sUL + mrow * 584 + ct * 16 + quad * 4) = pk;
    }
    __syncthreads();
    const int r = threadIdx.x >> 4;
    const int c0 = threadIdx.x & 15;
    if (nodeBase + r < n) {
      unsigned short* dst = UL + (size_t)(nodeBase + r) * 576;
      #pragma unroll
      for (int chunk = c0; chunk < 72; chunk += 16)
        *(short8*)(dst + chunk * 8) = *(const short8*)(sUL + r * 584 + chunk * 8);
    }
  }
}

// ---- conv gather phase: wave-stride over nodes; 1 uint load/edge (256B u0|u1 span)
template <bool HAS_RES, bool STORE_ANS, bool COMPUTE_T>
__device__ __forceinline__ void conv_phase(
    const unsigned short* __restrict__ UL,
    const int* __restrict__ cnt, const int* __restrict__ jw,
    const float* __restrict__ cb, const float* __restrict__ fb,
    const float* __restrict__ resid, const float* __restrict__ cW3,
    float* __restrict__ T, float* __restrict__ outAns,
    unsigned short* __restrict__ outAnsc, int n, int gwave, int NW) {
  const int lane = threadIdx.x & 63;
  const int half = lane >> 5;               // 0 -> u0 (w0), 1 -> u1 (w1)
  const int pl = lane & 31;
  const int c0i = 2 * pl, c1i = c0i + 1;
  const float cbf0 = cb[c0i] + fb[c0i];     // hoisted per phase
  const float cbf1 = cb[c1i] + fb[c1i];
  for (int i = gwave; i < n; i += NW) {
    int rec = jw[(size_t)i * CAP + (lane < CAP ? lane : 0)];
    const int m = min(cnt[i], CAP);
    const unsigned Lraw = ((const unsigned*)(UL + (size_t)i * 576 + 512))[pl];
    float rv0 = 0.0f, rv1 = 0.0f;
    if (HAS_RES) {
      float2 rv = *(const float2*)(resid + (size_t)i * 64 + 2 * pl);
      rv0 = rv.x; rv1 = rv.y;
    }
    float accLo = 0.0f, accHi = 0.0f;
    for (int q0 = 0; q0 < m; q0 += 16) {
      unsigned raw[16];
      float w0s[16];
      #pragma unroll
      for (int k = 0; k < 16; ++k) {        // issue all 16 loads before consuming
        int v = __builtin_amdgcn_readlane(rec, q0 + k);
        int j = min(v & 0x7FFF, n - 1);     // clamp garbage slots in-bounds
        int p = (v >> 15) & 7;
        w0s[k] = (float)((unsigned)v >> 18) * (1.0f / 16383.0f);
        raw[k] = ((const unsigned*)(UL + (size_t)j * 576 + p * 64))[lane];
      }
      #pragma unroll
      for (int k = 0; k < 16; ++k) {
        bool ok = (q0 + k < m);
        float w = half ? (1.0f - w0s[k]) : w0s[k];
        w = ok ? w : 0.0f;
        accLo = fmaf(w, __uint_as_float(raw[k] << 16), accLo);
        accHi = fmaf(w, __uint_as_float(raw[k] & 0xFFFF0000u), accHi);
      }
    }
    accLo += __shfl_xor(accLo, 32, 64);     // merge u0/u1 halves
    accHi += __shfl_xor(accHi, 32, 64);
    if (half == 0) {                        // lanes 0-31 do the epilogue
      float o0 = accLo + __uint_as_float(Lraw << 16) + cbf0 + rv0;
      float o1 = accHi + __uint_as_float(Lraw & 0xFFFF0000u) + cbf1 + rv1;
      if (STORE_ANS)
        *(float2*)(outAns + (size_t)i * 64 + c0i) = make_float2(o0, o1);
      unsigned short xb0 = (unsigned short)bf16s(fmaxf(o0, 0.0f));
      unsigned short xb1 = (unsigned short)bf16s(fmaxf(o1, 0.0f));
      ((unsigned*)(outAnsc + (size_t)i * 64))[pl] = (unsigned)xb0 | ((unsigned)xb1 << 16);
      if (COMPUTE_T) {
        float x0 = b2f(xb0), x1 = b2f(xb1);
        float c[16];
        #pragma unroll
        for (int t = 0; t < 16; ++t) {
          const float* wrow = cW3 + ((size_t)(t >> 1) * 64) * 2 + (t & 1);
          c[t] = x0 * wrow[c0i * 2] + x1 * wrow[c1i * 2];
        }
        #pragma unroll
        for (int off = 16; off > 0; off >>= 1) {
          #pragma unroll
          for (int t = 0; t < 16; ++t) c[t] += __shfl_xor(c[t], off, 64);
        }
        if (pl == 0) {
          float* tr = T + (size_t)i * 16;
          #pragma unroll
          for (int t = 0; t < 16; ++t) tr[t] = c[t];
        }
      }
    }
  }
}

// ================= the cooperative mega-kernel =================
__global__ __launch_bounds__(256, 4) void mega_kernel(MegaParams P) {
  cg::grid_group grid = cg::this_grid();
  __shared__ __align__(16) char smem[18688];
  const int tid = (int)(blockIdx.x * blockDim.x + threadIdx.x);
  const int NT = (int)(gridDim.x * blockDim.x);
  const int lane = threadIdx.x & 63;
  const int wIn = threadIdx.x >> 6;
  const int gwave = tid >> 6;
  const int NW = NT >> 6;
  const int n = P.n;

  // ---- Phase A1: zero cnt + build WTul1/2 [col][ch]
  for (int i = tid; i < n; i += NT) P.cnt[i] = 0;
  for (int idx = tid; idx < 2 * 576 * 64; idx += NT) {
    int sel = idx / (576 * 64);
    int r = idx - sel * (576 * 64);
    int col = r >> 6, ch = r & 63;
    const float* cW = sel ? P.cW2 : P.cW1;
    const float* fW = sel ? P.fW2 : P.fW1;
    float v;
    if (col < 512) {
      int p = col >> 6, co = col & 63;
      v = cW[((size_t)p * 64 + ch) * 64 + co];
    } else {
      v = fW[(size_t)ch * 64 + (col - 512)];
    }
    (sel ? P.wt2 : P.wt1)[(size_t)col * 64 + ch] = bf16s(v);
  }
  grid.sync();

  // ---- Phase A2: fill edge buckets
  for (int e = tid; e < P.nE; e += NT) {
    int i = P.fi[e], j = P.fj[e];
    if (i == j) continue;                  // centerIgnore
    float d = fminf(1.0f, fmaxf(-1.0f, P.dist[e]));
    float u = (d + 1.0f) * 3.5f;           // hat centers: spacing 2/7
    int p = min((int)u, 6);
    float w0 = 1.0f - (u - (float)p);
    int wq = (int)(w0 * 16383.0f + 0.5f);
    int pos = atomicAdd(&P.cnt[i], 1);
    if (pos < CAP)
      P.jw[(size_t)i * CAP + pos] = j | (p << 15) | (wq << 18);
  }
  grid.sync();

  // ---- Phase B: layer0 (4 nodes per block iteration, weights in LDS)
  {
    float* sW = (float*)smem;              // 1024
    float* sF = sW + 1024;                 // 128
    float* sB = sF + 128;                  // 64
    float* sacc = sB + 64;                 // 4*32
    for (int idx = threadIdx.x; idx < 1024; idx += 256) sW[idx] = P.cW0[idx];
    for (int idx = threadIdx.x; idx < 128; idx += 256) sF[idx] = P.fW0[idx];
    if (threadIdx.x < 32) sB[threadIdx.x] = P.cb0[threadIdx.x];
    else if (threadIdx.x < 64) sB[threadIdx.x] = P.fb0[threadIdx.x - 32];
    for (int g4 = blockIdx.x; g4 * 4 < n; g4 += gridDim.x) {
      const int i = g4 * 4 + wIn;
      const bool valid = (i < n);
      __syncthreads();                     // weights visible / sacc WAR guard
      if (valid && lane < 32) sacc[wIn * 32 + lane] = 0.0f;
      __syncthreads();
      if (valid && lane < min(P.cnt[i], CAP)) {
        int v = P.jw[(size_t)i * CAP + lane];
        int j = v & 0x7FFF;
        int p = (v >> 15) & 7;
        float w0 = (float)((unsigned)v >> 18) * (1.0f / 16383.0f);
        float w1 = 1.0f - w0;
        float4 x = *(const float4*)(P.X + (size_t)j * 4);
        atomicAdd(&sacc[wIn * 32 + p * 4 + 0], w0 * x.x);
        atomicAdd(&sacc[wIn * 32 + p * 4 + 1], w0 * x.y);
        atomicAdd(&sacc[wIn * 32 + p * 4 + 2], w0 * x.z);
        atomicAdd(&sacc[wIn * 32 + p * 4 + 3], w0 * x.w);
        atomicAdd(&sacc[wIn * 32 + (p + 1) * 4 + 0], w1 * x.x);
        atomicAdd(&sacc[wIn * 32 + (p + 1) * 4 + 1], w1 * x.y);
        atomicAdd(&sacc[wIn * 32 + (p + 1) * 4 + 2], w1 * x.z);
        atomicAdd(&sacc[wIn * 32 + (p + 1) * 4 + 3], w1 * x.w);
      }
      __syncthreads();
      if (valid) {
        const float4 xi = *(const float4*)(P.X + (size_t)i * 4);
        float v;
        if (lane < 32) {                   // lin -> channels 0..31
          v = sB[32 + lane];
          v = fmaf(xi.x, sF[0 * 32 + lane], v);
          v = fmaf(xi.y, sF[1 * 32 + lane], v);
          v = fmaf(xi.z, sF[2 * 32 + lane], v);
          v = fmaf(xi.w, sF[3 * 32 + lane], v);
        } else {                           // conv -> channels 32..63
          const int cc = lane - 32;
          v = sB[cc];
          #pragma unroll
          for (int k = 0; k < 32; ++k)
            v = fmaf(sacc[wIn * 32 + k], sW[k * 32 + cc], v);
        }
        P.ansc0[(size_t)i * 64 + lane] = (unsigned short)bf16s(fmaxf(v, 0.0f));
      }
    }
  }
  grid.sync();

  // ---- Phase C: gemm_ul layer 1
  gemm_ul_phase(P.ansc0, P.wt1, P.UL, n, smem);
  grid.sync();
  // ---- Phase D: conv layer 1
  conv_phase<false, true, false>(P.UL, P.cnt, P.jw, P.cb1, P.fb1,
                                 nullptr, nullptr, nullptr,
                                 P.ans1, P.ansc1, n, gwave, NW);
  grid.sync();
  // ---- Phase E: gemm_ul layer 2
  gemm_ul_phase(P.ansc1, P.wt2, P.UL, n, smem);
  grid.sync();
  // ---- Phase F: conv layer 2 (residual + fused T); ansc2 aliases ansc0
  conv_phase<true, false, true>(P.UL, P.cnt, P.jw, P.cb2, P.fb2,
                                P.ans1, P.cW3, P.T,
                                nullptr, P.ansc0, n, gwave, NW);
  grid.sync();
  // ---- Phase G: layer 3 (wave per node; lane = edge from T; + lin; reduce)
  {
    const unsigned short* Xb = P.ansc0;    // ansc2
    const float b3s0 = P.cb3[0] + P.fb3[0];
    const float b3s1 = P.cb3[1] + P.fb3[1];
    const float2 fw = *(const float2*)(P.fW3 + lane * 2);
    for (int i = gwave; i < n; i += NW) {
      const int m = min(P.cnt[i], CAP);
      float c0 = 0.0f, c1 = 0.0f;
      if (lane < m) {
        int v = P.jw[(size_t)i * CAP + lane];
        int j = min(v & 0x7FFF, n - 1);
        int p = (v >> 15) & 7;
        float w0 = (float)((unsigned)v >> 18) * (1.0f / 16383.0f);
        float w1 = 1.0f - w0;
        const float* tb = P.T + (size_t)j * 16 + p * 2;
        float2 ta = *(const float2*)(tb);
        float2 tc = *(const float2*)(tb + 2);
        c0 = w0 * ta.x + w1 * tc.x;
        c1 = w0 * ta.y + w1 * tc.y;
      }
      float xi = b2f(Xb[(size_t)i * 64 + lane]);
      c0 = fmaf(xi, fw.x, c0);
      c1 = fmaf(xi, fw.y, c1);
      #pragma unroll
      for (int off = 32; off > 0; off >>= 1) {
        c0 += __shfl_xor(c0, off, 64);
        c1 += __shfl_xor(c1, off, 64);
      }
      if (lane == 0) {
        P.out[(size_t)i * 2 + 0] = c0 + b3s0;
        P.out[(size_t)i * 2 + 1] = c1 + b3s1;
      }
    }
  }
}

extern "C" void kernel_launch(void* const* d_in, const int* in_sizes, int n_in,
                              void* d_out, int out_size, void* d_ws, size_t ws_size,
                              hipStream_t stream) {
  MegaParams P;
  P.X   = (const float*)d_in[0];
  P.fi  = (const int*)d_in[1];
  P.fj  = (const int*)d_in[2];
  P.dist = (const float*)d_in[3];
  P.cW0 = (const float*)d_in[4];  P.cb0 = (const float*)d_in[5];
  P.fW0 = (const float*)d_in[6];  P.fb0 = (const float*)d_in[7];
  P.cW1 = (const float*)d_in[8];  P.cb1 = (const float*)d_in[9];
  P.fW1 = (const float*)d_in[10]; P.fb1 = (const float*)d_in[11];
  P.cW2 = (const float*)d_in[12]; P.cb2 = (const float*)d_in[13];
  P.fW2 = (const float*)d_in[14]; P.fb2 = (const float*)d_in[15];
  P.cW3 = (const float*)d_in[16]; P.cb3 = (const float*)d_in[17];
  P.fW3 = (const float*)d_in[18]; P.fb3 = (const float*)d_in[19];
  P.out = (float*)d_out;

  const int n  = in_sizes[0] / 4;  // N = 30000
  const int nE = in_sizes[1];      // E = 480000
  P.n = n; P.nE = nE;

  // workspace layout (identical to r14, ~58 MB)
  unsigned short* UL    = (unsigned short*)d_ws;
  unsigned short* ansc0 = UL + (size_t)n * 576;
  unsigned short* ansc1 = ansc0 + (size_t)n * 64;
  float*          ans1  = (float*)(ansc1 + (size_t)n * 64);
  float* T     = ans1 + (size_t)n * 64;
  short* wt1   = (short*)(T + (size_t)n * 16);
  short* wt2   = wt1 + 576 * 64;
  int*   jw    = (int*)(wt2 + 576 * 64);
  int*   cnt   = jw + (size_t)n * CAP;
  P.UL = UL; P.ansc0 = ansc0; P.ansc1 = ansc1; P.ans1 = ans1;
  P.T = T; P.wt1 = wt1; P.wt2 = wt2; P.jw = jw; P.cnt = cnt;

  // co-resident grid sizing (occupancy-derived; conservative fallback)
  int perCU = 0;
  if (hipOccupancyMaxActiveBlocksPerMultiprocessor(
          &perCU, (const void*)mega_kernel, 256, 0) != hipSuccess || perCU < 1)
    perCU = 2;
  int numCU = 256;
  hipDeviceProp_t prop;
  int dev = 0;
  if (hipGetDevice(&dev) == hipSuccess &&
      hipGetDeviceProperties(&prop, dev) == hipSuccess)
    numCU = prop.multiProcessorCount;
  int blocks = perCU * numCU;
  if (blocks > 4096) blocks = 4096;

  void* args[] = { &P };
  hipLaunchCooperativeKernel((const void*)mega_kernel, dim3(blocks), dim3(256),
                             args, 0, stream);
}

// Round 16
// 269.256 us; speedup vs baseline: 2.7829x; 2.7829x over previous
//
#include <hip/hip_runtime.h>

// RbfNet on MI355X — round 16: r14 base (REVERT of r15's cooperative mega-kernel,
// which regressed 270->749us: grid.sync is a cross-XCD fence, 7 of them + lowest-
// common-denominator occupancy killed it). One change vs r14:
//   conv_gather waste slots (q0+k >= m in the fixed 16-deep batch) now clamp the
//   readlane INDEX to m-1 instead of reading garbage records -> their speculative
//   loads hit lines already in flight instead of touching ~54MB/layer of random UL.
// Structure: UL[j] = [x_j @ cW (p-major, 512) | x_j @ fW (64)] dense MFMA GEMM, then
// conv(x)[i] = sum_e w0*U[j,p] + w1*U[j,p+1]; layer3 via T[j][p] = ansc2[j] @ cW3[p].
// Edge record (4B): j(15b) | p(3b) | round(w0*16383)(14b); w1 = 1-w0. Self-edges dropped.

#define CAP 48

typedef __attribute__((ext_vector_type(8))) short short8;
typedef __attribute__((ext_vector_type(4))) short short4v;
typedef __attribute__((ext_vector_type(4))) float f32x4;

__device__ __forceinline__ short bf16s(float f) {   // fp32 -> bf16 RNE
  unsigned u = __float_as_uint(f);
  return (short)((u + 0x7FFF + ((u >> 16) & 1)) >> 16);
}
__device__ __forceinline__ float b2f(unsigned short s) {
  return __uint_as_float(((unsigned)s) << 16);
}

// ---------- fused: edge-bucket build (blocks < fillBlocks) + WTul prep (rest) ----------
__global__ void fill_prep(const float* __restrict__ dist,
                          const int* __restrict__ fi, const int* __restrict__ fj,
                          int* __restrict__ cnt, int* __restrict__ jw, int nE,
                          const float* __restrict__ cW1, const float* __restrict__ fW1,
                          const float* __restrict__ cW2, const float* __restrict__ fW2,
                          short* __restrict__ wt1, short* __restrict__ wt2,
                          int fillBlocks) {
  if ((int)blockIdx.x < fillBlocks) {
    int e = blockIdx.x * blockDim.x + threadIdx.x;
    if (e >= nE) return;
    int i = fi[e], j = fj[e];
    if (i == j) return;                  // centerIgnore
    float d = fminf(1.0f, fmaxf(-1.0f, dist[e]));
    float u = (d + 1.0f) * 3.5f;         // hat centers: spacing 2/7
    int p = min((int)u, 6);
    float w0 = 1.0f - (u - (float)p);
    int wq = (int)(w0 * 16383.0f + 0.5f);
    int pos = atomicAdd(&cnt[i], 1);
    if (pos < CAP)
      jw[(size_t)i * CAP + pos] = j | (p << 15) | (wq << 18);
  } else {
    int idx = ((int)blockIdx.x - fillBlocks) * blockDim.x + threadIdx.x;
    if (idx >= 2 * 576 * 64) return;
    int sel = idx / (576 * 64);
    int r = idx - sel * (576 * 64);
    int col = r >> 6, ch = r & 63;
    const float* cW = sel ? cW2 : cW1;
    const float* fW = sel ? fW2 : fW1;
    float v;
    if (col < 512) {
      int p = col >> 6, co = col & 63;
      v = cW[((size_t)p * 64 + ch) * 64 + co];
    } else {
      v = fW[(size_t)ch * 64 + (col - 512)];
    }
    (sel ? wt2 : wt1)[(size_t)col * 64 + ch] = bf16s(v);
  }
}

// ---------- layer 0: wave per node, lane-parallel edges, LDS fp32 atomics ----------
__global__ __launch_bounds__(256) void layer0_kernel(
    const float* __restrict__ X,      // [n,4] fp32
    const int* __restrict__ cnt, const int* __restrict__ jw,
    const float* __restrict__ cW0,    // [8*4*32]
    const float* __restrict__ cb0,
    const float* __restrict__ fW0,    // [4*32]
    const float* __restrict__ fb0,
    unsigned short* __restrict__ ansc0, int n) {    // [n,64] bf16 out
  __shared__ float sW[1024];
  __shared__ float sF[128];
  __shared__ float sB[64];
  __shared__ float sacc[4][32];
  for (int idx = threadIdx.x; idx < 1024; idx += 256) sW[idx] = cW0[idx];
  for (int idx = threadIdx.x; idx < 128; idx += 256) sF[idx] = fW0[idx];
  if (threadIdx.x < 32) sB[threadIdx.x] = cb0[threadIdx.x];
  else if (threadIdx.x < 64) sB[threadIdx.x] = fb0[threadIdx.x - 32];
  const int w = threadIdx.x >> 6;
  const int lane = threadIdx.x & 63;
  const int i = blockIdx.x * 4 + w;
  const bool valid = (i < n);
  if (valid && lane < 32) sacc[w][lane] = 0.0f;
  __syncthreads();
  if (valid && lane < min(cnt[i], CAP)) {   // lane = edge index
    int v = jw[(size_t)i * CAP + lane];
    int j = v & 0x7FFF;
    int p = (v >> 15) & 7;
    float w0 = (float)((unsigned)v >> 18) * (1.0f / 16383.0f);
    float w1 = 1.0f - w0;
    float4 x = *(const float4*)(X + (size_t)j * 4);
    atomicAdd(&sacc[w][p * 4 + 0], w0 * x.x);
    atomicAdd(&sacc[w][p * 4 + 1], w0 * x.y);
    atomicAdd(&sacc[w][p * 4 + 2], w0 * x.z);
    atomicAdd(&sacc[w][p * 4 + 3], w0 * x.w);
    atomicAdd(&sacc[w][(p + 1) * 4 + 0], w1 * x.x);
    atomicAdd(&sacc[w][(p + 1) * 4 + 1], w1 * x.y);
    atomicAdd(&sacc[w][(p + 1) * 4 + 2], w1 * x.z);
    atomicAdd(&sacc[w][(p + 1) * 4 + 3], w1 * x.w);
  }
  __syncthreads();
  if (!valid) return;
  const float4 xi = *(const float4*)(X + (size_t)i * 4);
  float v;
  if (lane < 32) {                    // lin -> channels 0..31
    v = sB[32 + lane];
    v = fmaf(xi.x, sF[0 * 32 + lane], v);
    v = fmaf(xi.y, sF[1 * 32 + lane], v);
    v = fmaf(xi.z, sF[2 * 32 + lane], v);
    v = fmaf(xi.w, sF[3 * 32 + lane], v);
  } else {                            // conv -> channels 32..63
    const int cc = lane - 32;
    v = sB[cc];
    #pragma unroll
    for (int k = 0; k < 32; ++k)
      v = fmaf(sacc[w][k], sW[k * 32 + cc], v);
  }
  ansc0[(size_t)i * 64 + lane] = (unsigned short)bf16s(fmaxf(v, 0.0f));
}

// ---------- dense MFMA GEMM: UL[n,576] = Xb[n,64] @ WTul^T ----------
__global__ __launch_bounds__(256) void gemm_ul(
    const unsigned short* __restrict__ Xb,  // [n,64] bf16
    const short* __restrict__ WTul,         // [576,64] bf16 (L2-resident)
    unsigned short* __restrict__ UL, int n) {
  __shared__ short sUL[16 * 584];
  const int lane = threadIdx.x & 63;
  const int w = threadIdx.x >> 6;
  const int mrow = lane & 15;
  const int quad = lane >> 4;
  const int nodeBase = blockIdx.x * 16;
  const int bnode = min(nodeBase + mrow, n - 1);
  const unsigned short* bBase = Xb + (size_t)bnode * 64 + quad * 8;
  short8 b0 = *(const short8*)(bBase);
  short8 b1 = *(const short8*)(bBase + 32);
  #pragma unroll
  for (int t = 0; t < 9; ++t) {
    const int ct = w * 9 + t;
    const short* aBase = WTul + (size_t)(ct * 16 + mrow) * 64 + quad * 8;
    short8 a0 = *(const short8*)(aBase);
    short8 a1 = *(const short8*)(aBase + 32);
    f32x4 acc = {0, 0, 0, 0};
    acc = __builtin_amdgcn_mfma_f32_16x16x32_bf16(a0, b0, acc, 0, 0, 0);
    acc = __builtin_amdgcn_mfma_f32_16x16x32_bf16(a1, b1, acc, 0, 0, 0);
    short4v pk;
    #pragma unroll
    for (int reg = 0; reg < 4; ++reg) pk[reg] = bf16s(acc[reg]);
    *(short4v*)(sUL + mrow * 584 + ct * 16 + quad * 4) = pk;
  }
  __syncthreads();
  const int r = threadIdx.x >> 4;
  const int c0 = threadIdx.x & 15;
  if (nodeBase + r < n) {
    unsigned short* dst = UL + (size_t)(nodeBase + r) * 576;
    #pragma unroll
    for (int chunk = c0; chunk < 72; chunk += 16)
      *(short8*)(dst + chunk * 8) = *(const short8*)(sUL + r * 584 + chunk * 8);
  }
}

// ---------- conv gather: wave per node; ONE uint load per edge (256B span = u0|u1) ----------
template <bool HAS_RES, bool STORE_ANS, bool COMPUTE_T>
__global__ __launch_bounds__(256) void conv_gather(
    const unsigned short* __restrict__ UL,  // [n,576] bf16
    const int* __restrict__ cnt, const int* __restrict__ jw,
    const float* __restrict__ cb, const float* __restrict__ fb,
    const float* __restrict__ resid,        // fp32 [n,64] or null
    const float* __restrict__ cW3,          // [8,64,2] (only if COMPUTE_T)
    float* __restrict__ T,                  // [n,16] fp32 (only if COMPUTE_T)
    float* __restrict__ outAns,             // fp32 [n,64] or null
    unsigned short* __restrict__ outAnsc, int n) {  // bf16 [n,64]
  const int lane = threadIdx.x & 63;
  const int half = lane >> 5;               // 0 -> u0 (w0), 1 -> u1 (w1)
  const int pl = lane & 31;                 // channel-pair index
  const int i = (blockIdx.x * blockDim.x + threadIdx.x) >> 6;
  if (i >= n) return;
  int rec = jw[(size_t)i * CAP + (lane < CAP ? lane : 0)];  // lane q holds record q
  const int m = min(cnt[i], CAP);
  const int mc = m - 1;                     // waste-slot clamp target (real record)
  const unsigned short* ULrow = UL + (size_t)i * 576;
  const unsigned Lraw = ((const unsigned*)(ULrow + 512))[pl];
  float rv0 = 0.0f, rv1 = 0.0f;
  if (HAS_RES) {
    float2 rv = *(const float2*)(resid + (size_t)i * 64 + 2 * pl);
    rv0 = rv.x; rv1 = rv.y;
  }
  float accLo = 0.0f, accHi = 0.0f;         // channels 2*pl, 2*pl+1 of this half
  for (int q0 = 0; q0 < m; q0 += 16) {
    unsigned raw[16];
    float w0s[16];
    #pragma unroll
    for (int k = 0; k < 16; ++k) {          // issue all 16 loads before consuming
      // clamp waste slots to the LAST REAL record: their loads dedup onto lines
      // already being fetched instead of touching random UL (weight masked below)
      int v = __builtin_amdgcn_readlane(rec, min(q0 + k, mc));
      int j = v & 0x7FFF;                   // record is real -> already in-bounds
      int p = (v >> 15) & 7;
      w0s[k] = (float)((unsigned)v >> 18) * (1.0f / 16383.0f);
      raw[k] = ((const unsigned*)(UL + (size_t)j * 576 + p * 64))[lane];
    }
    #pragma unroll
    for (int k = 0; k < 16; ++k) {
      bool ok = (q0 + k < m);
      float w = half ? (1.0f - w0s[k]) : w0s[k];
      w = ok ? w : 0.0f;
      accLo = fmaf(w, __uint_as_float(raw[k] << 16), accLo);
      accHi = fmaf(w, __uint_as_float(raw[k] & 0xFFFF0000u), accHi);
    }
  }
  accLo += __shfl_xor(accLo, 32, 64);       // merge u0/u1 halves
  accHi += __shfl_xor(accHi, 32, 64);
  if (half == 0) {                          // lanes 0-31 do the epilogue
    const int c0i = 2 * pl, c1i = c0i + 1;
    float L0 = __uint_as_float(Lraw << 16);
    float L1 = __uint_as_float(Lraw & 0xFFFF0000u);
    float o0 = accLo + L0 + cb[c0i] + fb[c0i] + rv0;
    float o1 = accHi + L1 + cb[c1i] + fb[c1i] + rv1;
    if (STORE_ANS)
      *(float2*)(outAns + (size_t)i * 64 + c0i) = make_float2(o0, o1);
    unsigned short xb0 = (unsigned short)bf16s(fmaxf(o0, 0.0f));
    unsigned short xb1 = (unsigned short)bf16s(fmaxf(o1, 0.0f));
    ((unsigned*)(outAnsc + (size_t)i * 64))[pl] = (unsigned)xb0 | ((unsigned)xb1 << 16);
    if (COMPUTE_T) {
      // T[i][t] = sum_ch ansc2[i,ch] * cW3[t>>1][ch][t&1], ansc2 read back through bf16
      float x0 = b2f(xb0), x1 = b2f(xb1);
      float c[16];
      #pragma unroll
      for (int t = 0; t < 16; ++t) {
        const float* wrow = cW3 + ((size_t)(t >> 1) * 64) * 2 + (t & 1);
        c[t] = x0 * wrow[c0i * 2] + x1 * wrow[c1i * 2];
      }
      #pragma unroll
      for (int off = 16; off > 0; off >>= 1) {   // butterfly within lanes 0-31
        #pragma unroll
        for (int t = 0; t < 16; ++t) c[t] += __shfl_xor(c[t], off, 64);
      }
      if (pl == 0) {
        float* tr = T + (size_t)i * 16;
        #pragma unroll
        for (int t = 0; t < 16; ++t) tr[t] = c[t];
      }
    }
  }
}

// ---------- layer 3: wave per node, lane = edge; 16B/edge from T; + lin; reduce ----------
__global__ __launch_bounds__(256, 4) void layer3_kernel(
    const unsigned short* __restrict__ Xb,  // ansc2 [n,64] bf16
    const float* __restrict__ T,            // [n,16] fp32
    const int* __restrict__ cnt, const int* __restrict__ jw,
    const float* __restrict__ cb3, const float* __restrict__ fb3,
    const float* __restrict__ fW3,          // [64,2]
    float* __restrict__ out, int n) {
  const int lane = threadIdx.x & 63;
  const int i = (blockIdx.x * blockDim.x + threadIdx.x) >> 6;
  if (i >= n) return;
  const int m = min(cnt[i], CAP);
  float c0 = 0.0f, c1 = 0.0f;
  if (lane < m) {                      // lane = edge index (fully lane-parallel)
    int v = jw[(size_t)i * CAP + lane];
    int j = min(v & 0x7FFF, n - 1);
    int p = (v >> 15) & 7;
    float w0 = (float)((unsigned)v >> 18) * (1.0f / 16383.0f);
    float w1 = 1.0f - w0;
    const float* tb = T + (size_t)j * 16 + p * 2;
    float2 ta = *(const float2*)(tb);
    float2 tc = *(const float2*)(tb + 2);
    c0 = w0 * ta.x + w1 * tc.x;
    c1 = w0 * ta.y + w1 * tc.y;
  }
  // linear path: lane = channel
  float xi = b2f(Xb[(size_t)i * 64 + lane]);
  float2 fw = *(const float2*)(fW3 + lane * 2);
  c0 = fmaf(xi, fw.x, c0);
  c1 = fmaf(xi, fw.y, c1);
  #pragma unroll
  for (int off = 32; off > 0; off >>= 1) {
    c0 += __shfl_xor(c0, off, 64);
    c1 += __shfl_xor(c1, off, 64);
  }
  if (lane == 0) {
    out[(size_t)i * 2 + 0] = c0 + cb3[0] + fb3[0];
    out[(size_t)i * 2 + 1] = c1 + cb3[1] + fb3[1];
  }
}

extern "C" void kernel_launch(void* const* d_in, const int* in_sizes, int n_in,
                              void* d_out, int out_size, void* d_ws, size_t ws_size,
                              hipStream_t stream) {
  const float* X    = (const float*)d_in[0];
  const int*   fi   = (const int*)d_in[1];
  const int*   fj   = (const int*)d_in[2];
  const float* dist = (const float*)d_in[3];
  const float* cW0 = (const float*)d_in[4];  const float* cb0 = (const float*)d_in[5];
  const float* fW0 = (const float*)d_in[6];  const float* fb0 = (const float*)d_in[7];
  const float* cW1 = (const float*)d_in[8];  const float* cb1 = (const float*)d_in[9];
  const float* fW1 = (const float*)d_in[10]; const float* fb1 = (const float*)d_in[11];
  const float* cW2 = (const float*)d_in[12]; const float* cb2 = (const float*)d_in[13];
  const float* fW2 = (const float*)d_in[14]; const float* fb2 = (const float*)d_in[15];
  const float* cW3 = (const float*)d_in[16]; const float* cb3 = (const float*)d_in[17];
  const float* fW3 = (const float*)d_in[18]; const float* fb3 = (const float*)d_in[19];
  float* out = (float*)d_out;

  const int n  = in_sizes[0] / 4;  // N = 30000
  const int nE = in_sizes[1];      // E = 480000

  // workspace (~58 MB): UL bf16[n*576] | ansc0 bf16[n*64] (alias ansc2) | ansc1 bf16[n*64]
  //   | ans1 fp32[n*64] | T fp32[n*16] | wtul1[576*64] | wtul2 | jw[n*CAP] | cnt[n]
  unsigned short* UL    = (unsigned short*)d_ws;
  unsigned short* ansc0 = UL + (size_t)n * 576;
  unsigned short* ansc1 = ansc0 + (size_t)n * 64;
  float*          ans1  = (float*)(ansc1 + (size_t)n * 64);
  unsigned short* ansc2 = ansc0;            // ansc0 dead after gemm_ul #1
  float* T     = ans1 + (size_t)n * 64;
  short* wtul1 = (short*)(T + (size_t)n * 16);
  short* wtul2 = wtul1 + 576 * 64;
  int*   jw    = (int*)(wtul2 + 576 * 64);
  int*   cnt   = jw + (size_t)n * CAP;

  hipMemsetAsync(cnt, 0, (size_t)n * sizeof(int), stream);
  const int fillBlocks = (nE + 255) / 256;
  const int prepBlocks = (2 * 576 * 64 + 255) / 256;
  fill_prep<<<fillBlocks + prepBlocks, 256, 0, stream>>>(
      dist, fi, fj, cnt, jw, nE, cW1, fW1, cW2, fW2, wtul1, wtul2, fillBlocks);

  // layer 0
  layer0_kernel<<<(n + 3) / 4, 256, 0, stream>>>(X, cnt, jw,
                                                 cW0, cb0, fW0, fb0, ansc0, n);
  // layer 1
  gemm_ul<<<(n + 15) / 16, 256, 0, stream>>>(ansc0, wtul1, UL, n);
  conv_gather<false, true, false><<<(n * 64 + 255) / 256, 256, 0, stream>>>(
      UL, cnt, jw, cb1, fb1, nullptr, nullptr, nullptr, ans1, ansc1, n);
  // layer 2 (residual) + fused T for layer 3
  gemm_ul<<<(n + 15) / 16, 256, 0, stream>>>(ansc1, wtul2, UL, n);
  conv_gather<true, false, true><<<(n * 64 + 255) / 256, 256, 0, stream>>>(
      UL, cnt, jw, cb2, fb2, ans1, cW3, T, nullptr, ansc2, n);
  // layer 3
  layer3_kernel<<<(n * 64 + 255) / 256, 256, 0, stream>>>(ansc2, T, cnt, jw,
                                                          cb3, fb3, fW3, out, n);
}

// Round 17
// 256.264 us; speedup vs baseline: 2.9239x; 1.0507x over previous
//
#include <hip/hip_runtime.h>

// RbfNet on MI355X — round 17: fuse layer0 + gemm_ul1 (dependency is node-local:
// UL1[i] needs only ansc0[i]). 16-node blocks: 4 waves x 4 nodes (edge loads batched
// across nodes for MLP), ansc0 tile kept in LDS bf16, gemm_ul MFMA tile in the same
// block epilogue. Kills 1 dispatch + the ansc0 global round-trip.
// conv_gather facts (r13/r14/r16): ~36us invariant to instruction mix = random-gather
// service floor for 480k x 256B from a 34.6MB table. r15 lesson: no cooperative sync.
// Structure: UL[j] = [x_j @ cW (p-major, 512) | x_j @ fW (64)]; conv(x)[i] =
// sum_e w0*U[j,p] + w1*U[j,p+1]; layer3 via T[j][p] = ansc2[j] @ cW3[p] (fused in conv2).
// Edge record (4B): j(15b) | p(3b) | round(w0*16383)(14b); w1 = 1-w0. Self-edges dropped.

#define CAP 48

typedef __attribute__((ext_vector_type(8))) short short8;
typedef __attribute__((ext_vector_type(4))) short short4v;
typedef __attribute__((ext_vector_type(4))) float f32x4;

__device__ __forceinline__ short bf16s(float f) {   // fp32 -> bf16 RNE
  unsigned u = __float_as_uint(f);
  return (short)((u + 0x7FFF + ((u >> 16) & 1)) >> 16);
}
__device__ __forceinline__ float b2f(unsigned short s) {
  return __uint_as_float(((unsigned)s) << 16);
}

// ---------- fused: edge-bucket build (blocks < fillBlocks) + WTul prep (rest) ----------
__global__ void fill_prep(const float* __restrict__ dist,
                          const int* __restrict__ fi, const int* __restrict__ fj,
                          int* __restrict__ cnt, int* __restrict__ jw, int nE,
                          const float* __restrict__ cW1, const float* __restrict__ fW1,
                          const float* __restrict__ cW2, const float* __restrict__ fW2,
                          short* __restrict__ wt1, short* __restrict__ wt2,
                          int fillBlocks) {
  if ((int)blockIdx.x < fillBlocks) {
    int e = blockIdx.x * blockDim.x + threadIdx.x;
    if (e >= nE) return;
    int i = fi[e], j = fj[e];
    if (i == j) return;                  // centerIgnore
    float d = fminf(1.0f, fmaxf(-1.0f, dist[e]));
    float u = (d + 1.0f) * 3.5f;         // hat centers: spacing 2/7
    int p = min((int)u, 6);
    float w0 = 1.0f - (u - (float)p);
    int wq = (int)(w0 * 16383.0f + 0.5f);
    int pos = atomicAdd(&cnt[i], 1);
    if (pos < CAP)
      jw[(size_t)i * CAP + pos] = j | (p << 15) | (wq << 18);
  } else {
    int idx = ((int)blockIdx.x - fillBlocks) * blockDim.x + threadIdx.x;
    if (idx >= 2 * 576 * 64) return;
    int sel = idx / (576 * 64);
    int r = idx - sel * (576 * 64);
    int col = r >> 6, ch = r & 63;
    const float* cW = sel ? cW2 : cW1;
    const float* fW = sel ? fW2 : fW1;
    float v;
    if (col < 512) {
      int p = col >> 6, co = col & 63;
      v = cW[((size_t)p * 64 + ch) * 64 + co];
    } else {
      v = fW[(size_t)ch * 64 + (col - 512)];
    }
    (sel ? wt2 : wt1)[(size_t)col * 64 + ch] = bf16s(v);
  }
}

// ---------- FUSED layer0 + gemm_ul1: 16 nodes/block, UL1 written directly ----------
__global__ __launch_bounds__(256) void layer0_gemm(
    const float* __restrict__ X,      // [n,4] fp32
    const int* __restrict__ cnt, const int* __restrict__ jw,
    const float* __restrict__ cW0,    // [8*4*32]
    const float* __restrict__ cb0,
    const float* __restrict__ fW0,    // [4*32]
    const float* __restrict__ fb0,
    const short* __restrict__ WTul,   // [576,64] bf16 layer-1 weights (L2-resident)
    unsigned short* __restrict__ UL, int n) {
  __shared__ float sW[1024];
  __shared__ float sF[128];
  __shared__ float sB[64];
  __shared__ float sacc[16][32];
  __shared__ __align__(16) unsigned short sXa[16 * 64];   // ansc0 tile, bf16
  __shared__ __align__(16) short sUL[16 * 584];           // UL staging
  const int w = threadIdx.x >> 6;
  const int lane = threadIdx.x & 63;
  const int nodeBase = blockIdx.x * 16;

  for (int idx = threadIdx.x; idx < 1024; idx += 256) sW[idx] = cW0[idx];
  for (int idx = threadIdx.x; idx < 128; idx += 256) sF[idx] = fW0[idx];
  if (threadIdx.x < 32) sB[threadIdx.x] = cb0[threadIdx.x];
  else if (threadIdx.x < 64) sB[threadIdx.x] = fb0[threadIdx.x - 32];
  sacc[threadIdx.x >> 5][threadIdx.x & 31] = 0.0f;
  sacc[8 + (threadIdx.x >> 5)][threadIdx.x & 31] = 0.0f;
  __syncthreads();

  // ---- edge gather for this wave's 4 nodes (loads batched across nodes for MLP)
  const int slot = (lane < CAP) ? lane : 0;
  int iN[4], mN[4], recN[4];
  #pragma unroll
  for (int s = 0; s < 4; ++s) {           // issue 4 independent jw-row + cnt loads
    iN[s] = nodeBase + w * 4 + s;
    const bool v = iN[s] < n;
    const int ic = v ? iN[s] : 0;
    mN[s] = v ? min(cnt[ic], CAP) : 0;
    recN[s] = jw[(size_t)ic * CAP + slot];
  }
  float4 xs[4];
  #pragma unroll
  for (int s = 0; s < 4; ++s) {           // issue 4 independent X gathers
    int j = min(recN[s] & 0x7FFF, n - 1); // garbage slots clamped in-bounds
    xs[s] = *(const float4*)(X + (size_t)j * 4);
  }
  #pragma unroll
  for (int s = 0; s < 4; ++s) {
    if (lane < mN[s]) {                   // lane = edge index
      int v = recN[s];
      int p = (v >> 15) & 7;
      float w0 = (float)((unsigned)v >> 18) * (1.0f / 16383.0f);
      float w1 = 1.0f - w0;
      float* a = sacc[w * 4 + s];
      atomicAdd(&a[p * 4 + 0], w0 * xs[s].x);
      atomicAdd(&a[p * 4 + 1], w0 * xs[s].y);
      atomicAdd(&a[p * 4 + 2], w0 * xs[s].z);
      atomicAdd(&a[p * 4 + 3], w0 * xs[s].w);
      atomicAdd(&a[(p + 1) * 4 + 0], w1 * xs[s].x);
      atomicAdd(&a[(p + 1) * 4 + 1], w1 * xs[s].y);
      atomicAdd(&a[(p + 1) * 4 + 2], w1 * xs[s].z);
      atomicAdd(&a[(p + 1) * 4 + 3], w1 * xs[s].w);
    }
  }
  __syncthreads();

  // ---- per-node outputs -> sXa (bf16); invalid nodes -> zeros
  #pragma unroll
  for (int s = 0; s < 4; ++s) {
    const int local = w * 4 + s;
    const int i = iN[s];
    float v = 0.0f;
    if (i < n) {
      const float4 xi = *(const float4*)(X + (size_t)i * 4);
      if (lane < 32) {                    // lin -> channels 0..31
        v = sB[32 + lane];
        v = fmaf(xi.x, sF[0 * 32 + lane], v);
        v = fmaf(xi.y, sF[1 * 32 + lane], v);
        v = fmaf(xi.z, sF[2 * 32 + lane], v);
        v = fmaf(xi.w, sF[3 * 32 + lane], v);
      } else {                            // conv -> channels 32..63
        const int cc = lane - 32;
        v = sB[cc];
        #pragma unroll
        for (int k = 0; k < 32; ++k)
          v = fmaf(sacc[local][k], sW[k * 32 + cc], v);
      }
      v = fmaxf(v, 0.0f);
    }
    sXa[local * 64 + lane] = (unsigned short)bf16s(v);
  }
  __syncthreads();

  // ---- gemm tile: UL[16,576] = sXa[16,64] @ WTul^T (B-fragment from LDS)
  const int mrow = lane & 15;
  const int quad = lane >> 4;
  short8 b0 = *(const short8*)(sXa + mrow * 64 + quad * 8);
  short8 b1 = *(const short8*)(sXa + mrow * 64 + quad * 8 + 32);
  #pragma unroll
  for (int t = 0; t < 9; ++t) {
    const int ct = w * 9 + t;
    const short* aBase = WTul + (size_t)(ct * 16 + mrow) * 64 + quad * 8;
    short8 a0 = *(const short8*)(aBase);
    short8 a1 = *(const short8*)(aBase + 32);
    f32x4 acc = {0, 0, 0, 0};
    acc = __builtin_amdgcn_mfma_f32_16x16x32_bf16(a0, b0, acc, 0, 0, 0);
    acc = __builtin_amdgcn_mfma_f32_16x16x32_bf16(a1, b1, acc, 0, 0, 0);
    short4v pk;
    #pragma unroll
    for (int reg = 0; reg < 4; ++reg) pk[reg] = bf16s(acc[reg]);
    *(short4v*)(sUL + mrow * 584 + ct * 16 + quad * 4) = pk;
  }
  __syncthreads();
  const int r = threadIdx.x >> 4;
  const int c0 = threadIdx.x & 15;
  if (nodeBase + r < n) {
    unsigned short* dst = UL + (size_t)(nodeBase + r) * 576;
    #pragma unroll
    for (int chunk = c0; chunk < 72; chunk += 16)
      *(short8*)(dst + chunk * 8) = *(const short8*)(sUL + r * 584 + chunk * 8);
  }
}

// ---------- dense MFMA GEMM: UL[n,576] = Xb[n,64] @ WTul^T (layer 2) ----------
__global__ __launch_bounds__(256) void gemm_ul(
    const unsigned short* __restrict__ Xb,  // [n,64] bf16
    const short* __restrict__ WTul,         // [576,64] bf16 (L2-resident)
    unsigned short* __restrict__ UL, int n) {
  __shared__ short sUL[16 * 584];
  const int lane = threadIdx.x & 63;
  const int w = threadIdx.x >> 6;
  const int mrow = lane & 15;
  const int quad = lane >> 4;
  const int nodeBase = blockIdx.x * 16;
  const int bnode = min(nodeBase + mrow, n - 1);
  const unsigned short* bBase = Xb + (size_t)bnode * 64 + quad * 8;
  short8 b0 = *(const short8*)(bBase);
  short8 b1 = *(const short8*)(bBase + 32);
  #pragma unroll
  for (int t = 0; t < 9; ++t) {
    const int ct = w * 9 + t;
    const short* aBase = WTul + (size_t)(ct * 16 + mrow) * 64 + quad * 8;
    short8 a0 = *(const short8*)(aBase);
    short8 a1 = *(const short8*)(aBase + 32);
    f32x4 acc = {0, 0, 0, 0};
    acc = __builtin_amdgcn_mfma_f32_16x16x32_bf16(a0, b0, acc, 0, 0, 0);
    acc = __builtin_amdgcn_mfma_f32_16x16x32_bf16(a1, b1, acc, 0, 0, 0);
    short4v pk;
    #pragma unroll
    for (int reg = 0; reg < 4; ++reg) pk[reg] = bf16s(acc[reg]);
    *(short4v*)(sUL + mrow * 584 + ct * 16 + quad * 4) = pk;
  }
  __syncthreads();
  const int r = threadIdx.x >> 4;
  const int c0 = threadIdx.x & 15;
  if (nodeBase + r < n) {
    unsigned short* dst = UL + (size_t)(nodeBase + r) * 576;
    #pragma unroll
    for (int chunk = c0; chunk < 72; chunk += 16)
      *(short8*)(dst + chunk * 8) = *(const short8*)(sUL + r * 584 + chunk * 8);
  }
}

// ---------- conv gather: wave per node; ONE uint load per edge (256B span = u0|u1) ----------
template <bool HAS_RES, bool STORE_ANS, bool COMPUTE_T>
__global__ __launch_bounds__(256) void conv_gather(
    const unsigned short* __restrict__ UL,  // [n,576] bf16
    const int* __restrict__ cnt, const int* __restrict__ jw,
    const float* __restrict__ cb, const float* __restrict__ fb,
    const float* __restrict__ resid,        // fp32 [n,64] or null
    const float* __restrict__ cW3,          // [8,64,2] (only if COMPUTE_T)
    float* __restrict__ T,                  // [n,16] fp32 (only if COMPUTE_T)
    float* __restrict__ outAns,             // fp32 [n,64] or null
    unsigned short* __restrict__ outAnsc, int n) {  // bf16 [n,64]
  const int lane = threadIdx.x & 63;
  const int half = lane >> 5;               // 0 -> u0 (w0), 1 -> u1 (w1)
  const int pl = lane & 31;                 // channel-pair index
  const int i = (blockIdx.x * blockDim.x + threadIdx.x) >> 6;
  if (i >= n) return;
  int rec = jw[(size_t)i * CAP + (lane < CAP ? lane : 0)];  // lane q holds record q
  const int m = min(cnt[i], CAP);
  const int mc = m - 1;                     // waste-slot clamp target (real record)
  const unsigned short* ULrow = UL + (size_t)i * 576;
  const unsigned Lraw = ((const unsigned*)(ULrow + 512))[pl];
  float rv0 = 0.0f, rv1 = 0.0f;
  if (HAS_RES) {
    float2 rv = *(const float2*)(resid + (size_t)i * 64 + 2 * pl);
    rv0 = rv.x; rv1 = rv.y;
  }
  float accLo = 0.0f, accHi = 0.0f;         // channels 2*pl, 2*pl+1 of this half
  for (int q0 = 0; q0 < m; q0 += 16) {
    unsigned raw[16];
    float w0s[16];
    #pragma unroll
    for (int k = 0; k < 16; ++k) {          // issue all 16 loads before consuming
      int v = __builtin_amdgcn_readlane(rec, min(q0 + k, mc));
      int j = v & 0x7FFF;                   // real record -> in-bounds
      int p = (v >> 15) & 7;
      w0s[k] = (float)((unsigned)v >> 18) * (1.0f / 16383.0f);
      raw[k] = ((const unsigned*)(UL + (size_t)j * 576 + p * 64))[lane];
    }
    #pragma unroll
    for (int k = 0; k < 16; ++k) {
      bool ok = (q0 + k < m);
      float w = half ? (1.0f - w0s[k]) : w0s[k];
      w = ok ? w : 0.0f;
      accLo = fmaf(w, __uint_as_float(raw[k] << 16), accLo);
      accHi = fmaf(w, __uint_as_float(raw[k] & 0xFFFF0000u), accHi);
    }
  }
  accLo += __shfl_xor(accLo, 32, 64);       // merge u0/u1 halves
  accHi += __shfl_xor(accHi, 32, 64);
  if (half == 0) {                          // lanes 0-31 do the epilogue
    const int c0i = 2 * pl, c1i = c0i + 1;
    float L0 = __uint_as_float(Lraw << 16);
    float L1 = __uint_as_float(Lraw & 0xFFFF0000u);
    float o0 = accLo + L0 + cb[c0i] + fb[c0i] + rv0;
    float o1 = accHi + L1 + cb[c1i] + fb[c1i] + rv1;
    if (STORE_ANS)
      *(float2*)(outAns + (size_t)i * 64 + c0i) = make_float2(o0, o1);
    unsigned short xb0 = (unsigned short)bf16s(fmaxf(o0, 0.0f));
    unsigned short xb1 = (unsigned short)bf16s(fmaxf(o1, 0.0f));
    ((unsigned*)(outAnsc + (size_t)i * 64))[pl] = (unsigned)xb0 | ((unsigned)xb1 << 16);
    if (COMPUTE_T) {
      float x0 = b2f(xb0), x1 = b2f(xb1);
      float c[16];
      #pragma unroll
      for (int t = 0; t < 16; ++t) {
        const float* wrow = cW3 + ((size_t)(t >> 1) * 64) * 2 + (t & 1);
        c[t] = x0 * wrow[c0i * 2] + x1 * wrow[c1i * 2];
      }
      #pragma unroll
      for (int off = 16; off > 0; off >>= 1) {   // butterfly within lanes 0-31
        #pragma unroll
        for (int t = 0; t < 16; ++t) c[t] += __shfl_xor(c[t], off, 64);
      }
      if (pl == 0) {
        float* tr = T + (size_t)i * 16;
        #pragma unroll
        for (int t = 0; t < 16; ++t) tr[t] = c[t];
      }
    }
  }
}

// ---------- layer 3: wave per node, lane = edge; 16B/edge from T; + lin; reduce ----------
__global__ __launch_bounds__(256, 4) void layer3_kernel(
    const unsigned short* __restrict__ Xb,  // ansc2 [n,64] bf16
    const float* __restrict__ T,            // [n,16] fp32
    const int* __restrict__ cnt, const int* __restrict__ jw,
    const float* __restrict__ cb3, const float* __restrict__ fb3,
    const float* __restrict__ fW3,          // [64,2]
    float* __restrict__ out, int n) {
  const int lane = threadIdx.x & 63;
  const int i = (blockIdx.x * blockDim.x + threadIdx.x) >> 6;
  if (i >= n) return;
  const int m = min(cnt[i], CAP);
  float c0 = 0.0f, c1 = 0.0f;
  if (lane < m) {                      // lane = edge index (fully lane-parallel)
    int v = jw[(size_t)i * CAP + lane];
    int j = min(v & 0x7FFF, n - 1);
    int p = (v >> 15) & 7;
    float w0 = (float)((unsigned)v >> 18) * (1.0f / 16383.0f);
    float w1 = 1.0f - w0;
    const float* tb = T + (size_t)j * 16 + p * 2;
    float2 ta = *(const float2*)(tb);
    float2 tc = *(const float2*)(tb + 2);
    c0 = w0 * ta.x + w1 * tc.x;
    c1 = w0 * ta.y + w1 * tc.y;
  }
  // linear path: lane = channel
  float xi = b2f(Xb[(size_t)i * 64 + lane]);
  float2 fw = *(const float2*)(fW3 + lane * 2);
  c0 = fmaf(xi, fw.x, c0);
  c1 = fmaf(xi, fw.y, c1);
  #pragma unroll
  for (int off = 32; off > 0; off >>= 1) {
    c0 += __shfl_xor(c0, off, 64);
    c1 += __shfl_xor(c1, off, 64);
  }
  if (lane == 0) {
    out[(size_t)i * 2 + 0] = c0 + cb3[0] + fb3[0];
    out[(size_t)i * 2 + 1] = c1 + cb3[1] + fb3[1];
  }
}

extern "C" void kernel_launch(void* const* d_in, const int* in_sizes, int n_in,
                              void* d_out, int out_size, void* d_ws, size_t ws_size,
                              hipStream_t stream) {
  const float* X    = (const float*)d_in[0];
  const int*   fi   = (const int*)d_in[1];
  const int*   fj   = (const int*)d_in[2];
  const float* dist = (const float*)d_in[3];
  const float* cW0 = (const float*)d_in[4];  const float* cb0 = (const float*)d_in[5];
  const float* fW0 = (const float*)d_in[6];  const float* fb0 = (const float*)d_in[7];
  const float* cW1 = (const float*)d_in[8];  const float* cb1 = (const float*)d_in[9];
  const float* fW1 = (const float*)d_in[10]; const float* fb1 = (const float*)d_in[11];
  const float* cW2 = (const float*)d_in[12]; const float* cb2 = (const float*)d_in[13];
  const float* fW2 = (const float*)d_in[14]; const float* fb2 = (const float*)d_in[15];
  const float* cW3 = (const float*)d_in[16]; const float* cb3 = (const float*)d_in[17];
  const float* fW3 = (const float*)d_in[18]; const float* fb3 = (const float*)d_in[19];
  float* out = (float*)d_out;

  const int n  = in_sizes[0] / 4;  // N = 30000
  const int nE = in_sizes[1];      // E = 480000

  // workspace (~58 MB): UL bf16[n*576] | ansc2 bf16[n*64] | ansc1 bf16[n*64]
  //   | ans1 fp32[n*64] | T fp32[n*16] | wtul1[576*64] | wtul2 | jw[n*CAP] | cnt[n]
  unsigned short* UL    = (unsigned short*)d_ws;
  unsigned short* ansc2 = UL + (size_t)n * 576;     // conv2 output (layer3 input)
  unsigned short* ansc1 = ansc2 + (size_t)n * 64;
  float*          ans1  = (float*)(ansc1 + (size_t)n * 64);
  float* T     = ans1 + (size_t)n * 64;
  short* wtul1 = (short*)(T + (size_t)n * 16);
  short* wtul2 = wtul1 + 576 * 64;
  int*   jw    = (int*)(wtul2 + 576 * 64);
  int*   cnt   = jw + (size_t)n * CAP;

  hipMemsetAsync(cnt, 0, (size_t)n * sizeof(int), stream);
  const int fillBlocks = (nE + 255) / 256;
  const int prepBlocks = (2 * 576 * 64 + 255) / 256;
  fill_prep<<<fillBlocks + prepBlocks, 256, 0, stream>>>(
      dist, fi, fj, cnt, jw, nE, cW1, fW1, cW2, fW2, wtul1, wtul2, fillBlocks);

  // layer 0 + gemm_ul layer 1 (fused; UL1 written directly, no ansc0 round-trip)
  layer0_gemm<<<(n + 15) / 16, 256, 0, stream>>>(X, cnt, jw, cW0, cb0, fW0, fb0,
                                                 wtul1, UL, n);
  // layer 1 conv
  conv_gather<false, true, false><<<(n * 64 + 255) / 256, 256, 0, stream>>>(
      UL, cnt, jw, cb1, fb1, nullptr, nullptr, nullptr, ans1, ansc1, n);
  // layer 2
  gemm_ul<<<(n + 15) / 16, 256, 0, stream>>>(ansc1, wtul2, UL, n);
  conv_gather<true, false, true><<<(n * 64 + 255) / 256, 256, 0, stream>>>(
      UL, cnt, jw, cb2, fb2, ans1, cW3, T, nullptr, ansc2, n);
  // layer 3
  layer3_kernel<<<(n * 64 + 255) / 256, 256, 0, stream>>>(ansc2, T, cnt, jw,
                                                          cb3, fb3, fW3, out, n);
}